// Round 8
// baseline (1034.558 us; speedup 1.0000x reference)
//
#include <hip/hip_runtime.h>
#include <math.h>

#define HH 64
#define WW 64
#define NIMG 4
#define CIN 512
#define AA 9
#define HWA (HH*WW*AA)          // 36864
#define PRE_NMS 6000
#define POST_NMS 300
#define NEGV (-1e10f)
#define NEGK 0xD01502F9u        // descending-order key of -1e10f
#define NWORD 94                // ceil(6000/64)

#define OFF1 589824             // rpn_scores
#define OFF2 884736             // rois
#define OFF3 889536             // roi_indices
#define OFF4 890736             // anchors

typedef unsigned int u32;
typedef unsigned long long u64;
typedef _Float16 f16;
typedef _Float16 half8 __attribute__((ext_vector_type(8)));
typedef float f32x4 __attribute__((ext_vector_type(4)));

__device__ __forceinline__ void gload_lds16(const void* g, void* l)
{
    __builtin_amdgcn_global_load_lds((const __attribute__((address_space(1))) void*)g,
                                     (__attribute__((address_space(3))) void*)l,
                                     16, 0, 0);
}

// ---------------- prep: x[n][ci][y][xc] f32 -> x_t[n][y][xc][ci] fp16 hi/lo ----------
__global__ __launch_bounds__(256) void k_prep_x(const float* __restrict__ x,
                                                f16* __restrict__ xh,
                                                f16* __restrict__ xl)
{
    __shared__ float tile[64][65];
    int ci0 = blockIdx.x * 64, y = blockIdx.y, n = blockIdx.z;
    int t = threadIdx.x;
    #pragma unroll
    for (int l = 0; l < 16; ++l) {
        int idx = l * 256 + t;
        int cc = idx >> 6, xc = idx & 63;
        tile[cc][xc] = x[((size_t)(n * CIN + ci0 + cc) * HH + y) * WW + xc];
    }
    __syncthreads();
    #pragma unroll
    for (int l = 0; l < 16; ++l) {
        int idx = l * 256 + t;
        int xc = idx >> 6, cc = idx & 63;
        float v = tile[cc][xc];
        f16 hi = (f16)v;
        f16 lo = (f16)(v - (float)hi);
        size_t o = ((size_t)(n * 64 + y) * 64 + xc) * 512 + ci0 + cc;
        xh[o] = hi; xl[o] = lo;
    }
}

// ---------------- prep: W1[co][ci][tap] f32 -> W2[tap][co][ci] fp16 hi/lo ----------
__global__ __launch_bounds__(256) void k_prep_w(const float* __restrict__ W1,
                                                f16* __restrict__ wh,
                                                f16* __restrict__ wl)
{
    int idx = blockIdx.x * 256 + threadIdx.x;   // 512*512
    int co = idx >> 9, ci = idx & 511;
    #pragma unroll
    for (int tap = 0; tap < 9; ++tap) {
        float v = W1[(size_t)idx * 9 + tap];
        f16 hi = (f16)v;
        f16 lo = (f16)(v - (float)hi);
        size_t o = ((size_t)tap * 512 + co) * 512 + ci;
        wh[o] = hi; wl[o] = lo;
    }
}

// ---------------- conv3x3 via MFMA fp16x3 implicit GEMM (single-buffer, 4 blk/CU) ---
// Grid (yb=32, co=8, n=4): linear_id % 8 == yb % 8, so all 8 co-tiles sharing the
// same x rows land on the SAME XCD -> x staged traffic hits that XCD's L2.
__global__ __launch_bounds__(256, 4) void k_conv_mfma(const f16* __restrict__ xh,
                                                      const f16* __restrict__ xl,
                                                      const f16* __restrict__ wh,
                                                      const f16* __restrict__ wl,
                                                      const float* __restrict__ bias,
                                                      float* __restrict__ mid)
{
    __shared__ f16 sX[2][4][64][32];   // [plane][row y0-1..y0+2][col][ci] = 32768 B
    const int t = threadIdx.x;
    const int yb = blockIdx.x, co0 = blockIdx.y * 64, n = blockIdx.z;
    const int y0 = yb * 2;
    const int wv = t >> 6, lane = t & 63;
    const int q = lane >> 4, li = lane & 15;
    const int mh = wv & 1;             // co half (32 co)
    const int xhp = wv >> 1;           // px half (32 px)

    // pre-zero vertical-halo rows (never written by masked prefetch)
    if (yb == 0 || yb == 31) {
        int rowu = (yb == 0) ? 0 : 3072;           // u32 offset of row 0 / row 3
        u32* p = (u32*)&sX[0][0][0][0];
        #pragma unroll
        for (int l = 0; l < 8; ++l) {
            int idx = l * 256 + t;                 // 0..2047
            int plane = idx >> 10, r = idx & 1023;
            p[plane * 4096 + rowu + r] = 0;
        }
    }

    f32x4 acc[2][2][2];   // [mt][xn][yy]
    #pragma unroll
    for (int mt = 0; mt < 2; ++mt)
        #pragma unroll
        for (int xn = 0; xn < 2; ++xn)
            #pragma unroll
            for (int yy = 0; yy < 2; ++yy)
                acc[mt][xn][yy] = (f32x4){0.f, 0.f, 0.f, 0.f};

    // staging: 32 wave-insts x 1 KB = both planes, 4 rows, 64 cols, 32 ci
    auto prefetch = [&](int ci0) {
        #pragma unroll
        for (int m = 0; m < 8; ++m) {
            int k2 = wv * 8 + m;               // 0..31, wave-uniform
            int plane = k2 >> 4;
            int row = (k2 >> 2) & 3;
            int gy = y0 - 1 + row;
            if ((unsigned)gy < 64u) {
                int col = ((k2 & 3) << 4) + (lane >> 2);
                int s = lane & 3;
                const f16* src = (plane ? xl : xh) +
                    (((size_t)(n * 64 + gy) * 64 + col) * 512 + ci0 + s * 8);
                f16* dst = &sX[0][0][0][0] + (size_t)k2 * 512 + lane * 8;
                gload_lds16(src, dst);
            }
        }
    };

    half8 wa[2][2], wn[2][2];    // [plane][mt]
    auto loadW = [&](half8 w[2][2], int ci0, int tap) {
        #pragma unroll
        for (int mt = 0; mt < 2; ++mt) {
            size_t base = ((size_t)(tap * 512) + co0 + mh * 32 + mt * 16 + li) * 512 + ci0 + q * 8;
            w[0][mt] = *(const half8*)(wh + base);
            w[1][mt] = *(const half8*)(wl + base);
        }
    };

    prefetch(0);
    loadW(wa, 0, 0);

    const half8 zero8 = {(f16)0, (f16)0, (f16)0, (f16)0, (f16)0, (f16)0, (f16)0, (f16)0};

    for (int chunk = 0; chunk < 16; ++chunk) {
        const int ci0 = chunk * 32;
        __syncthreads();                       // data ready (vmcnt+lgkm drained)

        #pragma unroll
        for (int tap = 0; tap < 9; ++tap) {
            if (tap < 8) loadW(wn, ci0, tap + 1);
            const int ky = tap / 3, kx = tap - ky * 3;

            half8 B[2][2][2];                  // [plane][xn][yy]
            #pragma unroll
            for (int xn = 0; xn < 2; ++xn) {
                int xc = xhp * 32 + xn * 16 + li;
                int colr = xc + kx - 1;
                bool oob = (colr < 0) || (colr > 63);
                int colc = oob ? 0 : colr;
                #pragma unroll
                for (int yy = 0; yy < 2; ++yy) {
                    int row = yy + ky;
                    const f16* ph = &sX[0][row][colc][q * 8];
                    half8 vh = *(const half8*)ph;
                    half8 vl = *(const half8*)(ph + 8192);
                    if (oob) { vh = zero8; vl = zero8; }
                    B[0][xn][yy] = vh; B[1][xn][yy] = vl;
                }
            }
            #pragma unroll
            for (int mt = 0; mt < 2; ++mt)
                #pragma unroll
                for (int xn = 0; xn < 2; ++xn)
                    #pragma unroll
                    for (int yy = 0; yy < 2; ++yy)
                        acc[mt][xn][yy] = __builtin_amdgcn_mfma_f32_16x16x32_f16(wa[0][mt], B[0][xn][yy], acc[mt][xn][yy], 0, 0, 0);
            #pragma unroll
            for (int mt = 0; mt < 2; ++mt)
                #pragma unroll
                for (int xn = 0; xn < 2; ++xn)
                    #pragma unroll
                    for (int yy = 0; yy < 2; ++yy)
                        acc[mt][xn][yy] = __builtin_amdgcn_mfma_f32_16x16x32_f16(wa[0][mt], B[1][xn][yy], acc[mt][xn][yy], 0, 0, 0);
            #pragma unroll
            for (int mt = 0; mt < 2; ++mt)
                #pragma unroll
                for (int xn = 0; xn < 2; ++xn)
                    #pragma unroll
                    for (int yy = 0; yy < 2; ++yy)
                        acc[mt][xn][yy] = __builtin_amdgcn_mfma_f32_16x16x32_f16(wa[1][mt], B[0][xn][yy], acc[mt][xn][yy], 0, 0, 0);

            if (tap < 8) {
                #pragma unroll
                for (int pl = 0; pl < 2; ++pl)
                    #pragma unroll
                    for (int mt = 0; mt < 2; ++mt) wa[pl][mt] = wn[pl][mt];
            }
        }

        if (chunk + 1 < 16) {
            __syncthreads();                   // compute done, safe to overwrite sX
            prefetch(ci0 + 32);
            loadW(wa, ci0 + 32, 0);
        }
    }

    // epilogue: D row=q*4+r -> co, col=li -> px; bias + relu
    #pragma unroll
    for (int mt = 0; mt < 2; ++mt) {
        #pragma unroll
        for (int r = 0; r < 4; ++r) {
            int co = co0 + mh * 32 + mt * 16 + q * 4 + r;
            float bv = bias[co];
            #pragma unroll
            for (int xn = 0; xn < 2; ++xn) {
                int xc = xhp * 32 + xn * 16 + li;
                #pragma unroll
                for (int yy = 0; yy < 2; ++yy) {
                    float v = acc[mt][xn][yy][r] + bv;
                    mid[((size_t)(n * 512 + co) * HH + y0 + yy) * WW + xc] = v > 0.f ? v : 0.f;
                }
            }
        }
    }
}

// ---------------- head weights -> [ci][co] (co: 0..17 score, 18..53 loc, pad 64) ----
__global__ __launch_bounds__(256) void k_htrans(const float* __restrict__ Ws,
                                                const float* __restrict__ Wl,
                                                float* __restrict__ Wt2)
{
    int i = blockIdx.x * 256 + threadIdx.x;   // 512*64
    if (i >= 512 * 64) return;
    int ci = i >> 6, co = i & 63;
    float v = 0.f;
    if (co < 18) v = Ws[co * 512 + ci];
    else if (co < 54) v = Wl[(co - 18) * 512 + ci];
    Wt2[i] = v;
}

// ---------------- 1x1 heads as GEMM: sraw[n][co64][px4096] ----------------
__global__ __launch_bounds__(256) void k_hgemm(const float* __restrict__ mid,
                                               const float* __restrict__ Wt2,
                                               float* __restrict__ sraw)
{
    __shared__ float sM[32][64];   // [ci][px]
    __shared__ float sW2[32][64];  // [ci][co]
    const int t = threadIdx.x;
    const int px0 = blockIdx.x * 64, n = blockIdx.y;
    const int tx = t & 15, ty = t >> 4;

    float acc[4][4];
    #pragma unroll
    for (int c = 0; c < 4; ++c)
        #pragma unroll
        for (int j = 0; j < 4; ++j) acc[c][j] = 0.f;

    for (int ci0 = 0; ci0 < 512; ci0 += 32) {
        __syncthreads();
        #pragma unroll
        for (int l = 0; l < 8; ++l) {
            int i = l * 256 + t;
            int ci = i >> 6, px = i & 63;
            sM[ci][px] = mid[((size_t)n * 512 + ci0 + ci) * 4096 + px0 + px];
            sW2[ci][px] = Wt2[(size_t)(ci0 + ci) * 64 + px];
        }
        __syncthreads();
        #pragma unroll
        for (int ci = 0; ci < 32; ++ci) {
            float mv[4], wv[4];
            #pragma unroll
            for (int j = 0; j < 4; ++j) mv[j] = sM[ci][tx * 4 + j];
            #pragma unroll
            for (int c = 0; c < 4; ++c) wv[c] = sW2[ci][ty * 4 + c];
            #pragma unroll
            for (int c = 0; c < 4; ++c)
                #pragma unroll
                for (int j = 0; j < 4; ++j) acc[c][j] += wv[c] * mv[j];
        }
    }
    #pragma unroll
    for (int c = 0; c < 4; ++c) {
        float4 v = make_float4(acc[c][0], acc[c][1], acc[c][2], acc[c][3]);
        *(float4*)&sraw[((size_t)n * 64 + ty * 4 + c) * 4096 + px0 + tx * 4] = v;
    }
}

// ---------------- decode: softmax, loc2bbox, clip, keys, head outputs ----------------
__global__ __launch_bounds__(256) void k_decode(const float* __restrict__ sraw,
                                                const float* __restrict__ bsc,
                                                const float* __restrict__ blc,
                                                const int* __restrict__ ph,
                                                const int* __restrict__ pw,
                                                float* __restrict__ out,
                                                float* __restrict__ boxes,
                                                u32* __restrict__ key)
{
    int p = blockIdx.x * 256 + threadIdx.x;   // 0..16383
    int n = p >> 12, pi = p & 4095;
    int y = pi >> 6, xq = pi & 63;

    const float* S = sraw + (size_t)n * 64 * 4096 + pi;
    float* o0 = out + (size_t)n * 147456;
    float* o1 = out + OFF1 + (size_t)n * 73728;
    float IHf = (float)(*ph), IWf = (float)(*pw);

    #pragma unroll
    for (int a = 0; a < 9; ++a) {
        float s0 = S[(size_t)(2 * a) * 4096] + bsc[2 * a];
        float s1 = S[(size_t)(2 * a + 1) * 4096] + bsc[2 * a + 1];
        float dy = S[(size_t)(18 + 4 * a) * 4096] + blc[4 * a];
        float dx = S[(size_t)(19 + 4 * a) * 4096] + blc[4 * a + 1];
        float dh = S[(size_t)(20 + 4 * a) * 4096] + blc[4 * a + 2];
        float dw = S[(size_t)(21 + 4 * a) * 4096] + blc[4 * a + 3];

        o1[(pi * 9 + a) * 2 + 0] = s0;
        o1[(pi * 9 + a) * 2 + 1] = s1;
        o0[(pi * 9 + a) * 4 + 0] = dy;
        o0[(pi * 9 + a) * 4 + 1] = dx;
        o0[(pi * 9 + a) * 4 + 2] = dh;
        o0[(pi * 9 + a) * 4 + 3] = dw;

        // softmax fg (max-subtracted like jax.nn.softmax)
        float mm = fmaxf(s0, s1);
        float e0 = expf(s0 - mm), e1 = expf(s1 - mm);
        float fg = e1 / (e0 + e1);

        // anchor (base in f64 like numpy, then f32 add of exact shift)
        int ri = a / 3, si = a - ri * 3;
        double s = (double)(8 << si);
        double rr = (ri == 0) ? 0.5 : ((ri == 1) ? 1.0 : 2.0);
        double hh = 16.0 * s * sqrt(rr);
        double wd = 16.0 * s * sqrt(1.0 / rr);
        float a0 = (float)(8.0 - hh * 0.5) + (float)(y * 16);
        float a1 = (float)(8.0 - wd * 0.5) + (float)(xq * 16);
        float a2 = (float)(8.0 + hh * 0.5) + (float)(y * 16);
        float a3 = (float)(8.0 + wd * 0.5) + (float)(xq * 16);

        // loc2bbox
        float h = a2 - a0, w = a3 - a1;
        float cy = a0 + 0.5f * h, cx = a1 + 0.5f * w;
        float ncy = dy * h + cy, ncx = dx * w + cx;
        float nh = expf(dh) * h, nw = expf(dw) * w;
        float b0 = fminf(fmaxf(ncy - 0.5f * nh, 0.f), IHf);
        float b1 = fminf(fmaxf(ncx - 0.5f * nw, 0.f), IWf);
        float b2 = fminf(fmaxf(ncy + 0.5f * nh, 0.f), IHf);
        float b3 = fminf(fmaxf(ncx + 0.5f * nw, 0.f), IWf);

        bool ok = (b2 - b0 >= 16.0f) && (b3 - b1 >= 16.0f);
        float sc = ok ? fg : NEGV;

        int gi = n * HWA + pi * 9 + a;
        ((float4*)boxes)[gi] = make_float4(b0, b1, b2, b3);
        u32 u = __float_as_uint(sc);
        u32 kasc = (u & 0x80000000u) ? ~u : (u | 0x80000000u);
        key[gi] = ~kasc;   // ascending key == descending score
    }
}

// ---------------- anchors out + roi_indices + zero rois ----------------
__global__ void k_misc(float* __restrict__ out)
{
    int i = blockIdx.x * 256 + threadIdx.x;
    if (i < 4800) out[OFF2 + i] = 0.f;
    if (i < 1200) out[OFF3 + i] = (float)(i / 300);
    if (i < HWA) {
        int pi = i / 9, a = i - pi * 9;
        int y = pi >> 6, xq = pi & 63;
        int ri = a / 3, si = a - ri * 3;
        double s = (double)(8 << si);
        double rr = (ri == 0) ? 0.5 : ((ri == 1) ? 1.0 : 2.0);
        double hh = 16.0 * s * sqrt(rr);
        double wd = 16.0 * s * sqrt(1.0 / rr);
        out[OFF4 + i * 4 + 0] = (float)(8.0 - hh * 0.5) + (float)(y * 16);
        out[OFF4 + i * 4 + 1] = (float)(8.0 - wd * 0.5) + (float)(xq * 16);
        out[OFF4 + i * 4 + 2] = (float)(8.0 + hh * 0.5) + (float)(y * 16);
        out[OFF4 + i * 4 + 3] = (float)(8.0 + wd * 0.5) + (float)(xq * 16);
    }
}

// ---------------- exact rank-6000 radix select + compact ----------------
__global__ __launch_bounds__(1024) void k_select(const u32* __restrict__ key,
                                                 u64* __restrict__ cmp,
                                                 int* __restrict__ nvalid)
{
    __shared__ int hist[256];
    __shared__ u32 sPref;
    __shared__ int sR;
    __shared__ int cLess, cEq, cVal;
    int n = blockIdx.x, t = threadIdx.x;
    const u32* k0 = key + (size_t)n * HWA;

    u32 pref = 0, mask = 0;
    int R = PRE_NMS;
    for (int pass = 0; pass < 4; ++pass) {
        int shift = 24 - pass * 8;
        if (t < 256) hist[t] = 0;
        __syncthreads();
        for (int i = t; i < HWA; i += 1024) {
            u32 k = k0[i];
            if ((k & mask) == pref) atomicAdd(&hist[(k >> shift) & 255], 1);
        }
        __syncthreads();
        if (t == 0) {
            int cum = 0;
            for (int b = 0; b < 256; ++b) {
                int c = hist[b];
                if (cum + c >= R) { sPref = pref | ((u32)b << shift); sR = R - cum; break; }
                cum += c;
            }
        }
        __syncthreads();
        pref = sPref; R = sR; mask |= (0xFFu << shift);
        __syncthreads();
    }
    u32 T = pref;   // exact 6000th smallest key
    if (t == 0) { cLess = 0; cEq = 0; cVal = 0; }
    __syncthreads();
    for (int i = t; i < HWA; i += 1024) {
        u32 k = k0[i];
        if (k < NEGK) atomicAdd(&cVal, 1);
        if (k < T) {
            int p = atomicAdd(&cLess, 1);
            cmp[(size_t)n * 8192 + p] = ((u64)k << 32) | (u32)i;
        } else if (k == T) {
            int p = atomicAdd(&cEq, 1);
            if (p < R) cmp[(size_t)n * 8192 + (PRE_NMS - 1 - p)] = ((u64)k << 32) | (u32)i;
        }
    }
    __syncthreads();
    if (t == 0) nvalid[n] = cVal < PRE_NMS ? cVal : PRE_NMS;
}

// ---------------- rank-by-count ordering (replaces bitonic sort) ----------------
// rank[i] = #{j in [0,6000): cmp[j] < cmp[i]} (u64 unique -> exact permutation).
// Ascending u64 = descending score with index tiebreak = lax.top_k order.
__global__ __launch_bounds__(64) void k_rank(const u64* __restrict__ cmp,
                                             const float* __restrict__ boxes,
                                             float* __restrict__ boxesS)
{
    int n = blockIdx.y;
    int i = blockIdx.x * 64 + threadIdx.x;
    if (i >= PRE_NMS) return;
    const u64* K = cmp + (size_t)n * 8192;
    u64 ki = K[i];
    int rank = 0;
    #pragma unroll 8
    for (int j = 0; j < PRE_NMS; ++j)
        rank += (K[j] < ki) ? 1 : 0;
    u32 idx = (u32)(ki & 0xFFFFFFFFu);
    ((float4*)boxesS)[(size_t)n * PRE_NMS + rank] =
        ((const float4*)boxes)[(size_t)n * HWA + idx];
}

// ---------------- IoU suppression bitmask: mask[n][i][w], upper triangle only ------
__global__ __launch_bounds__(64) void k_iou(const float* __restrict__ boxesS,
                                            u64* __restrict__ mask)
{
    __shared__ float4 cb[64];
    int w = blockIdx.x, ic = blockIdx.y, n = blockIdx.z;
    if (w < ic) return;                       // strictly-lower triangle: unused
    int t = threadIdx.x;
    const float4* B = (const float4*)boxesS + (size_t)n * PRE_NMS;
    int jc = w * 64 + t;
    cb[t] = (jc < PRE_NMS) ? B[jc] : make_float4(0.f, 0.f, 0.f, 0.f);
    __syncthreads();
    int i = ic * 64 + t;
    if (i >= PRE_NMS) return;
    float4 bb = B[i];
    float area1 = (bb.z - bb.x) * (bb.w - bb.y);
    u64 m = 0;
    #pragma unroll 8
    for (int j = 0; j < 64; ++j) {
        float4 o = cb[j];
        float ty_ = fmaxf(bb.x, o.x), tx_ = fmaxf(bb.y, o.y);
        float by_ = fminf(bb.z, o.z), bx_ = fminf(bb.w, o.w);
        float inter = fmaxf(by_ - ty_, 0.f) * fmaxf(bx_ - tx_, 0.f);
        float area2 = (o.z - o.x) * (o.w - o.y);
        float iou = inter / (area1 + area2 - inter + 1e-9f);
        if (iou > 0.7f) m |= (1ull << j);
    }
    mask[((size_t)n * PRE_NMS + i) * NWORD + w] = m;
}

// ---------------- batched greedy bitmask NMS: single wave, 8 candidates/round ------
// Equivalent to sequential greedy: candidates are the 8 lowest clear bits at round
// start; chaining processes them ascending, ORing each selected row before checking
// the next -- exactly the greedy recurrence.
__global__ __launch_bounds__(64) void k_nms4(const u64* __restrict__ mask,
                                             const int* __restrict__ nvalid,
                                             const float* __restrict__ boxesS,
                                             float* __restrict__ rois)
{
    int n = blockIdx.x, lane = threadIdx.x;
    int nv = nvalid[n];
    const u64* M = mask + (size_t)n * PRE_NMS * NWORD;
    const float4* B = (const float4*)boxesS + (size_t)n * PRE_NMS;

    auto vmask = [&](int w) -> u64 {
        int lo = w * 64;
        if (nv >= lo + 64) return ~0ull;
        if (nv <= lo) return 0ull;
        return (1ull << (nv - lo)) - 1ull;
    };
    u64 vm0 = vmask(lane);
    u64 vm1 = (lane < NWORD - 64) ? vmask(64 + lane) : 0ull;
    u64 rem0 = 0, rem1 = 0;

    int cnt = 0;
    while (cnt < POST_NMS) {
        // extract up to 8 lowest clear candidates
        u64 t0 = (~rem0) & vm0;
        u64 t1 = (~rem1) & vm1;
        int cand[8];
        int nc = 0;
        #pragma unroll
        for (int k = 0; k < 8; ++k) {
            u64 b0 = __ballot(t0 != 0);
            int c = -1;
            if (b0) {
                int l = __builtin_ctzll(b0);
                u64 w = __shfl(t0, l);
                c = l * 64 + __builtin_ctzll(w);
                if (lane == l) t0 &= t0 - 1;
            } else {
                u64 b1 = __ballot(t1 != 0);
                if (b1) {
                    int l = __builtin_ctzll(b1);
                    u64 w = __shfl(t1, l);
                    c = (64 + l) * 64 + __builtin_ctzll(w);
                    if (lane == l) t1 &= t1 - 1;
                }
            }
            if (c < 0) break;
            cand[nc++] = c;
        }
        if (nc == 0) break;

        // gather rows for all candidates (one latency window)
        u64 r0[8], r1[8];
        for (int k = 0; k < nc; ++k) {
            const u64* Mr = M + (size_t)cand[k] * NWORD;
            r0[k] = Mr[lane];
            r1[k] = (lane < NWORD - 64) ? Mr[64 + lane] : 0ull;
        }

        // chain greedily
        for (int k = 0; k < nc && cnt < POST_NMS; ++k) {
            int c = cand[k];
            int w = c >> 6, b = c & 63;
            u64 cw = (w < 64) ? __shfl(rem0, w) : __shfl(rem1, w - 64);
            if (!((cw >> b) & 1ull)) {
                if (lane == 0) {
                    float4 bb = B[c];
                    float* orow = rois + (size_t)(n * POST_NMS + cnt) * 4;
                    orow[0] = bb.x; orow[1] = bb.y; orow[2] = bb.z; orow[3] = bb.w;
                }
                rem0 |= r0[k];
                rem1 |= r1[k];
                cnt++;
            }
        }
    }
}

extern "C" void kernel_launch(void* const* d_in, const int* in_sizes, int n_in,
                              void* d_out, int out_size, void* d_ws, size_t ws_size,
                              hipStream_t stream)
{
    const float* x  = (const float*)d_in[0];
    const float* W1 = (const float*)d_in[1];
    const float* b1 = (const float*)d_in[2];
    const float* Ws = (const float*)d_in[3];
    const float* bs = (const float*)d_in[4];
    const float* Wl = (const float*)d_in[5];
    const float* bl = (const float*)d_in[6];
    const int* ih   = (const int*)d_in[7];
    const int* iw   = (const int*)d_in[8];
    float* out = (float*)d_out;
    char* ws = (char*)d_ws;

    // during conv:
    f16*   Wh2    = (f16*)  (ws);                 //  4,718,592 B (dead after conv)
    f16*   Wl2    = (f16*)  (ws + 4718592);       //  4,718,592 B (dead after conv)
    float* mid    = (float*)(ws + 9437184);       // 33,554,432 B (dead after hgemm)
    f16*   xh     = (f16*)  (ws + 42991616);      // 16,777,216 B (dead after conv)
    f16*   xl     = (f16*)  (ws + 59768832);      // 16,777,216 B (dead after conv)
    // after conv (reusing xh region at identical old offsets):
    float* boxes  = (float*)(ws + 42991616);      //  2,359,296 B
    u32*   key    = (u32*)  (ws + 45350912);      //    589,824 B
    u64*   cmp    = (u64*)  (ws + 45940736);      //    262,144 B
    float* boxesS = (float*)(ws + 46202880);      //    384,000 B
    int*   nval   = (int*)  (ws + 46586880);      //         16 B
    // reuse dead Wh2 region after conv:
    float* Wt2    = (float*)(ws);                 //    131,072 B [ci][co64]
    float* sraw   = (float*)(ws + 262144);        //  4,194,304 B [n][co64][px]
    // reuse dead mid region after hgemm:
    u64*   iomask = (u64*)  (ws + 9437184);       // 18,048,000 B

    k_prep_x<<<dim3(8, 64, 4), 256, 0, stream>>>(x, xh, xl);
    k_prep_w<<<1024, 256, 0, stream>>>(W1, Wh2, Wl2);
    k_conv_mfma<<<dim3(32, 8, 4), 256, 0, stream>>>(xh, xl, Wh2, Wl2, b1, mid);
    k_htrans<<<128, 256, 0, stream>>>(Ws, Wl, Wt2);
    k_hgemm<<<dim3(64, 4), 256, 0, stream>>>(mid, Wt2, sraw);
    k_decode<<<64, 256, 0, stream>>>(sraw, bs, bl, ih, iw, out, boxes, key);
    k_misc<<<144, 256, 0, stream>>>(out);
    k_select<<<4, 1024, 0, stream>>>(key, cmp, nval);
    k_rank<<<dim3(94, NIMG), 64, 0, stream>>>(cmp, boxes, boxesS);
    k_iou<<<dim3(NWORD, NWORD, NIMG), 64, 0, stream>>>(boxesS, iomask);
    k_nms4<<<NIMG, 64, 0, stream>>>(iomask, nval, boxesS, out + OFF2);
}

// Round 9
// 915.653 us; speedup vs baseline: 1.1299x; 1.1299x over previous
//
#include <hip/hip_runtime.h>
#include <math.h>

#define HH 64
#define WW 64
#define NIMG 4
#define CIN 512
#define AA 9
#define HWA (HH*WW*AA)          // 36864
#define PRE_NMS 6000
#define POST_NMS 300
#define NEGV (-1e10f)
#define NEGK 0xD01502F9u        // descending-order key of -1e10f
#define NWORD 94                // ceil(6000/64)

#define OFF1 589824             // rpn_scores
#define OFF2 884736             // rois
#define OFF3 889536             // roi_indices
#define OFF4 890736             // anchors

typedef unsigned int u32;
typedef unsigned long long u64;
typedef _Float16 f16;
typedef _Float16 half8 __attribute__((ext_vector_type(8)));
typedef float f32x4 __attribute__((ext_vector_type(4)));

__device__ __forceinline__ void gload_lds16(const void* g, void* l)
{
    __builtin_amdgcn_global_load_lds((const __attribute__((address_space(1))) void*)g,
                                     (__attribute__((address_space(3))) void*)l,
                                     16, 0, 0);
}

// ---------------- prep: x[n][ci][y][xc] f32 -> x_t[n][y][xc][ci] fp16 hi/lo ----------
__global__ __launch_bounds__(256) void k_prep_x(const float* __restrict__ x,
                                                f16* __restrict__ xh,
                                                f16* __restrict__ xl)
{
    __shared__ float tile[64][65];
    int ci0 = blockIdx.x * 64, y = blockIdx.y, n = blockIdx.z;
    int t = threadIdx.x;
    #pragma unroll
    for (int l = 0; l < 16; ++l) {
        int idx = l * 256 + t;
        int cc = idx >> 6, xc = idx & 63;
        tile[cc][xc] = x[((size_t)(n * CIN + ci0 + cc) * HH + y) * WW + xc];
    }
    __syncthreads();
    #pragma unroll
    for (int l = 0; l < 16; ++l) {
        int idx = l * 256 + t;
        int xc = idx >> 6, cc = idx & 63;
        float v = tile[cc][xc];
        f16 hi = (f16)v;
        f16 lo = (f16)(v - (float)hi);
        size_t o = ((size_t)(n * 64 + y) * 64 + xc) * 512 + ci0 + cc;
        xh[o] = hi; xl[o] = lo;
    }
}

// ---------------- prep: W1[co][ci][tap] f32 -> W2[tap][co][ci] fp16 hi/lo ----------
__global__ __launch_bounds__(256) void k_prep_w(const float* __restrict__ W1,
                                                f16* __restrict__ wh,
                                                f16* __restrict__ wl)
{
    int idx = blockIdx.x * 256 + threadIdx.x;   // 512*512
    int co = idx >> 9, ci = idx & 511;
    #pragma unroll
    for (int tap = 0; tap < 9; ++tap) {
        float v = W1[(size_t)idx * 9 + tap];
        f16 hi = (f16)v;
        f16 lo = (f16)(v - (float)hi);
        size_t o = ((size_t)tap * 512 + co) * 512 + ci;
        wh[o] = hi; wl[o] = lo;
    }
}

// ---------------- conv3x3 via MFMA fp16x3 implicit GEMM (single-buffer, 4 blk/CU) ---
// Grid (yb=32, co=8, n=4): linear_id % 8 == yb % 8, so all 8 co-tiles sharing the
// same x rows land on the SAME XCD -> x staged traffic hits that XCD's L2.
__global__ __launch_bounds__(256, 4) void k_conv_mfma(const f16* __restrict__ xh,
                                                      const f16* __restrict__ xl,
                                                      const f16* __restrict__ wh,
                                                      const f16* __restrict__ wl,
                                                      const float* __restrict__ bias,
                                                      float* __restrict__ mid)
{
    __shared__ f16 sX[2][4][64][32];   // [plane][row y0-1..y0+2][col][ci] = 32768 B
    const int t = threadIdx.x;
    const int yb = blockIdx.x, co0 = blockIdx.y * 64, n = blockIdx.z;
    const int y0 = yb * 2;
    const int wv = t >> 6, lane = t & 63;
    const int q = lane >> 4, li = lane & 15;
    const int mh = wv & 1;             // co half (32 co)
    const int xhp = wv >> 1;           // px half (32 px)

    // pre-zero vertical-halo rows (never written by masked prefetch)
    if (yb == 0 || yb == 31) {
        int rowu = (yb == 0) ? 0 : 3072;           // u32 offset of row 0 / row 3
        u32* p = (u32*)&sX[0][0][0][0];
        #pragma unroll
        for (int l = 0; l < 8; ++l) {
            int idx = l * 256 + t;                 // 0..2047
            int plane = idx >> 10, r = idx & 1023;
            p[plane * 4096 + rowu + r] = 0;
        }
    }

    f32x4 acc[2][2][2];   // [mt][xn][yy]
    #pragma unroll
    for (int mt = 0; mt < 2; ++mt)
        #pragma unroll
        for (int xn = 0; xn < 2; ++xn)
            #pragma unroll
            for (int yy = 0; yy < 2; ++yy)
                acc[mt][xn][yy] = (f32x4){0.f, 0.f, 0.f, 0.f};

    // staging: 32 wave-insts x 1 KB = both planes, 4 rows, 64 cols, 32 ci
    auto prefetch = [&](int ci0) {
        #pragma unroll
        for (int m = 0; m < 8; ++m) {
            int k2 = wv * 8 + m;               // 0..31, wave-uniform
            int plane = k2 >> 4;
            int row = (k2 >> 2) & 3;
            int gy = y0 - 1 + row;
            if ((unsigned)gy < 64u) {
                int col = ((k2 & 3) << 4) + (lane >> 2);
                int s = lane & 3;
                const f16* src = (plane ? xl : xh) +
                    (((size_t)(n * 64 + gy) * 64 + col) * 512 + ci0 + s * 8);
                f16* dst = &sX[0][0][0][0] + (size_t)k2 * 512 + lane * 8;
                gload_lds16(src, dst);
            }
        }
    };

    half8 wa[2][2], wn[2][2];    // [plane][mt]
    auto loadW = [&](half8 w[2][2], int ci0, int tap) {
        #pragma unroll
        for (int mt = 0; mt < 2; ++mt) {
            size_t base = ((size_t)(tap * 512) + co0 + mh * 32 + mt * 16 + li) * 512 + ci0 + q * 8;
            w[0][mt] = *(const half8*)(wh + base);
            w[1][mt] = *(const half8*)(wl + base);
        }
    };

    prefetch(0);
    loadW(wa, 0, 0);

    const half8 zero8 = {(f16)0, (f16)0, (f16)0, (f16)0, (f16)0, (f16)0, (f16)0, (f16)0};

    for (int chunk = 0; chunk < 16; ++chunk) {
        const int ci0 = chunk * 32;
        __syncthreads();                       // data ready (vmcnt+lgkm drained)

        #pragma unroll
        for (int tap = 0; tap < 9; ++tap) {
            if (tap < 8) loadW(wn, ci0, tap + 1);
            const int ky = tap / 3, kx = tap - ky * 3;

            half8 B[2][2][2];                  // [plane][xn][yy]
            #pragma unroll
            for (int xn = 0; xn < 2; ++xn) {
                int xc = xhp * 32 + xn * 16 + li;
                int colr = xc + kx - 1;
                bool oob = (colr < 0) || (colr > 63);
                int colc = oob ? 0 : colr;
                #pragma unroll
                for (int yy = 0; yy < 2; ++yy) {
                    int row = yy + ky;
                    const f16* ph = &sX[0][row][colc][q * 8];
                    half8 vh = *(const half8*)ph;
                    half8 vl = *(const half8*)(ph + 8192);
                    if (oob) { vh = zero8; vl = zero8; }
                    B[0][xn][yy] = vh; B[1][xn][yy] = vl;
                }
            }
            #pragma unroll
            for (int mt = 0; mt < 2; ++mt)
                #pragma unroll
                for (int xn = 0; xn < 2; ++xn)
                    #pragma unroll
                    for (int yy = 0; yy < 2; ++yy)
                        acc[mt][xn][yy] = __builtin_amdgcn_mfma_f32_16x16x32_f16(wa[0][mt], B[0][xn][yy], acc[mt][xn][yy], 0, 0, 0);
            #pragma unroll
            for (int mt = 0; mt < 2; ++mt)
                #pragma unroll
                for (int xn = 0; xn < 2; ++xn)
                    #pragma unroll
                    for (int yy = 0; yy < 2; ++yy)
                        acc[mt][xn][yy] = __builtin_amdgcn_mfma_f32_16x16x32_f16(wa[0][mt], B[1][xn][yy], acc[mt][xn][yy], 0, 0, 0);
            #pragma unroll
            for (int mt = 0; mt < 2; ++mt)
                #pragma unroll
                for (int xn = 0; xn < 2; ++xn)
                    #pragma unroll
                    for (int yy = 0; yy < 2; ++yy)
                        acc[mt][xn][yy] = __builtin_amdgcn_mfma_f32_16x16x32_f16(wa[1][mt], B[0][xn][yy], acc[mt][xn][yy], 0, 0, 0);

            if (tap < 8) {
                #pragma unroll
                for (int pl = 0; pl < 2; ++pl)
                    #pragma unroll
                    for (int mt = 0; mt < 2; ++mt) wa[pl][mt] = wn[pl][mt];
            }
        }

        if (chunk + 1 < 16) {
            __syncthreads();                   // compute done, safe to overwrite sX
            prefetch(ci0 + 32);
            loadW(wa, ci0 + 32, 0);
        }
    }

    // epilogue: D row=q*4+r -> co, col=li -> px; bias + relu
    #pragma unroll
    for (int mt = 0; mt < 2; ++mt) {
        #pragma unroll
        for (int r = 0; r < 4; ++r) {
            int co = co0 + mh * 32 + mt * 16 + q * 4 + r;
            float bv = bias[co];
            #pragma unroll
            for (int xn = 0; xn < 2; ++xn) {
                int xc = xhp * 32 + xn * 16 + li;
                #pragma unroll
                for (int yy = 0; yy < 2; ++yy) {
                    float v = acc[mt][xn][yy][r] + bv;
                    mid[((size_t)(n * 512 + co) * HH + y0 + yy) * WW + xc] = v > 0.f ? v : 0.f;
                }
            }
        }
    }
}

// ---------------- head weights -> [ci][co] (co: 0..17 score, 18..53 loc, pad 64) ----
__global__ __launch_bounds__(256) void k_htrans(const float* __restrict__ Ws,
                                                const float* __restrict__ Wl,
                                                float* __restrict__ Wt2)
{
    int i = blockIdx.x * 256 + threadIdx.x;   // 512*64
    if (i >= 512 * 64) return;
    int ci = i >> 6, co = i & 63;
    float v = 0.f;
    if (co < 18) v = Ws[co * 512 + ci];
    else if (co < 54) v = Wl[(co - 18) * 512 + ci];
    Wt2[i] = v;
}

// ---------------- 1x1 heads as GEMM: sraw[n][co64][px4096] ----------------
__global__ __launch_bounds__(256) void k_hgemm(const float* __restrict__ mid,
                                               const float* __restrict__ Wt2,
                                               float* __restrict__ sraw)
{
    __shared__ float sM[32][64];   // [ci][px]
    __shared__ float sW2[32][64];  // [ci][co]
    const int t = threadIdx.x;
    const int px0 = blockIdx.x * 64, n = blockIdx.y;
    const int tx = t & 15, ty = t >> 4;

    float acc[4][4];
    #pragma unroll
    for (int c = 0; c < 4; ++c)
        #pragma unroll
        for (int j = 0; j < 4; ++j) acc[c][j] = 0.f;

    for (int ci0 = 0; ci0 < 512; ci0 += 32) {
        __syncthreads();
        #pragma unroll
        for (int l = 0; l < 8; ++l) {
            int i = l * 256 + t;
            int ci = i >> 6, px = i & 63;
            sM[ci][px] = mid[((size_t)n * 512 + ci0 + ci) * 4096 + px0 + px];
            sW2[ci][px] = Wt2[(size_t)(ci0 + ci) * 64 + px];
        }
        __syncthreads();
        #pragma unroll
        for (int ci = 0; ci < 32; ++ci) {
            float mv[4], wv[4];
            #pragma unroll
            for (int j = 0; j < 4; ++j) mv[j] = sM[ci][tx * 4 + j];
            #pragma unroll
            for (int c = 0; c < 4; ++c) wv[c] = sW2[ci][ty * 4 + c];
            #pragma unroll
            for (int c = 0; c < 4; ++c)
                #pragma unroll
                for (int j = 0; j < 4; ++j) acc[c][j] += wv[c] * mv[j];
        }
    }
    #pragma unroll
    for (int c = 0; c < 4; ++c) {
        float4 v = make_float4(acc[c][0], acc[c][1], acc[c][2], acc[c][3]);
        *(float4*)&sraw[((size_t)n * 64 + ty * 4 + c) * 4096 + px0 + tx * 4] = v;
    }
}

// ---------------- decode: softmax, loc2bbox, clip, keys, head outputs ----------------
__global__ __launch_bounds__(256) void k_decode(const float* __restrict__ sraw,
                                                const float* __restrict__ bsc,
                                                const float* __restrict__ blc,
                                                const int* __restrict__ ph,
                                                const int* __restrict__ pw,
                                                float* __restrict__ out,
                                                float* __restrict__ boxes,
                                                u32* __restrict__ key)
{
    int p = blockIdx.x * 256 + threadIdx.x;   // 0..16383
    int n = p >> 12, pi = p & 4095;
    int y = pi >> 6, xq = pi & 63;

    const float* S = sraw + (size_t)n * 64 * 4096 + pi;
    float* o0 = out + (size_t)n * 147456;
    float* o1 = out + OFF1 + (size_t)n * 73728;
    float IHf = (float)(*ph), IWf = (float)(*pw);

    #pragma unroll
    for (int a = 0; a < 9; ++a) {
        float s0 = S[(size_t)(2 * a) * 4096] + bsc[2 * a];
        float s1 = S[(size_t)(2 * a + 1) * 4096] + bsc[2 * a + 1];
        float dy = S[(size_t)(18 + 4 * a) * 4096] + blc[4 * a];
        float dx = S[(size_t)(19 + 4 * a) * 4096] + blc[4 * a + 1];
        float dh = S[(size_t)(20 + 4 * a) * 4096] + blc[4 * a + 2];
        float dw = S[(size_t)(21 + 4 * a) * 4096] + blc[4 * a + 3];

        o1[(pi * 9 + a) * 2 + 0] = s0;
        o1[(pi * 9 + a) * 2 + 1] = s1;
        o0[(pi * 9 + a) * 4 + 0] = dy;
        o0[(pi * 9 + a) * 4 + 1] = dx;
        o0[(pi * 9 + a) * 4 + 2] = dh;
        o0[(pi * 9 + a) * 4 + 3] = dw;

        // softmax fg (max-subtracted like jax.nn.softmax)
        float mm = fmaxf(s0, s1);
        float e0 = expf(s0 - mm), e1 = expf(s1 - mm);
        float fg = e1 / (e0 + e1);

        // anchor (base in f64 like numpy, then f32 add of exact shift)
        int ri = a / 3, si = a - ri * 3;
        double s = (double)(8 << si);
        double rr = (ri == 0) ? 0.5 : ((ri == 1) ? 1.0 : 2.0);
        double hh = 16.0 * s * sqrt(rr);
        double wd = 16.0 * s * sqrt(1.0 / rr);
        float a0 = (float)(8.0 - hh * 0.5) + (float)(y * 16);
        float a1 = (float)(8.0 - wd * 0.5) + (float)(xq * 16);
        float a2 = (float)(8.0 + hh * 0.5) + (float)(y * 16);
        float a3 = (float)(8.0 + wd * 0.5) + (float)(xq * 16);

        // loc2bbox
        float h = a2 - a0, w = a3 - a1;
        float cy = a0 + 0.5f * h, cx = a1 + 0.5f * w;
        float ncy = dy * h + cy, ncx = dx * w + cx;
        float nh = expf(dh) * h, nw = expf(dw) * w;
        float b0 = fminf(fmaxf(ncy - 0.5f * nh, 0.f), IHf);
        float b1 = fminf(fmaxf(ncx - 0.5f * nw, 0.f), IWf);
        float b2 = fminf(fmaxf(ncy + 0.5f * nh, 0.f), IHf);
        float b3 = fminf(fmaxf(ncx + 0.5f * nw, 0.f), IWf);

        bool ok = (b2 - b0 >= 16.0f) && (b3 - b1 >= 16.0f);
        float sc = ok ? fg : NEGV;

        int gi = n * HWA + pi * 9 + a;
        ((float4*)boxes)[gi] = make_float4(b0, b1, b2, b3);
        u32 u = __float_as_uint(sc);
        u32 kasc = (u & 0x80000000u) ? ~u : (u | 0x80000000u);
        key[gi] = ~kasc;   // ascending key == descending score
    }
}

// ---------------- anchors out + roi_indices + zero rois ----------------
__global__ void k_misc(float* __restrict__ out)
{
    int i = blockIdx.x * 256 + threadIdx.x;
    if (i < 4800) out[OFF2 + i] = 0.f;
    if (i < 1200) out[OFF3 + i] = (float)(i / 300);
    if (i < HWA) {
        int pi = i / 9, a = i - pi * 9;
        int y = pi >> 6, xq = pi & 63;
        int ri = a / 3, si = a - ri * 3;
        double s = (double)(8 << si);
        double rr = (ri == 0) ? 0.5 : ((ri == 1) ? 1.0 : 2.0);
        double hh = 16.0 * s * sqrt(rr);
        double wd = 16.0 * s * sqrt(1.0 / rr);
        out[OFF4 + i * 4 + 0] = (float)(8.0 - hh * 0.5) + (float)(y * 16);
        out[OFF4 + i * 4 + 1] = (float)(8.0 - wd * 0.5) + (float)(xq * 16);
        out[OFF4 + i * 4 + 2] = (float)(8.0 + hh * 0.5) + (float)(y * 16);
        out[OFF4 + i * 4 + 3] = (float)(8.0 + wd * 0.5) + (float)(xq * 16);
    }
}

// ---------------- exact rank-6000 radix select + compact ----------------
__global__ __launch_bounds__(1024) void k_select(const u32* __restrict__ key,
                                                 u64* __restrict__ cmp,
                                                 int* __restrict__ nvalid)
{
    __shared__ int hist[256];
    __shared__ u32 sPref;
    __shared__ int sR;
    __shared__ int cLess, cEq, cVal;
    int n = blockIdx.x, t = threadIdx.x;
    const u32* k0 = key + (size_t)n * HWA;

    u32 pref = 0, mask = 0;
    int R = PRE_NMS;
    for (int pass = 0; pass < 4; ++pass) {
        int shift = 24 - pass * 8;
        if (t < 256) hist[t] = 0;
        __syncthreads();
        for (int i = t; i < HWA; i += 1024) {
            u32 k = k0[i];
            if ((k & mask) == pref) atomicAdd(&hist[(k >> shift) & 255], 1);
        }
        __syncthreads();
        if (t == 0) {
            int cum = 0;
            for (int b = 0; b < 256; ++b) {
                int c = hist[b];
                if (cum + c >= R) { sPref = pref | ((u32)b << shift); sR = R - cum; break; }
                cum += c;
            }
        }
        __syncthreads();
        pref = sPref; R = sR; mask |= (0xFFu << shift);
        __syncthreads();
    }
    u32 T = pref;   // exact 6000th smallest key
    if (t == 0) { cLess = 0; cEq = 0; cVal = 0; }
    __syncthreads();
    for (int i = t; i < HWA; i += 1024) {
        u32 k = k0[i];
        if (k < NEGK) atomicAdd(&cVal, 1);
        if (k < T) {
            int p = atomicAdd(&cLess, 1);
            cmp[(size_t)n * 8192 + p] = ((u64)k << 32) | (u32)i;
        } else if (k == T) {
            int p = atomicAdd(&cEq, 1);
            if (p < R) cmp[(size_t)n * 8192 + (PRE_NMS - 1 - p)] = ((u64)k << 32) | (u32)i;
        }
    }
    __syncthreads();
    if (t == 0) nvalid[n] = cVal < PRE_NMS ? cVal : PRE_NMS;
}

// ---------------- rank-by-count ordering, LDS-staged ----------------
// rank[i] = #{j: cmp[j] < cmp[i]} over the 6000 compacted u64 keys (unique ->
// exact permutation; ascending u64 = descending score + index tiebreak =
// lax.top_k order). Keys staged once into 48 KB LDS; inner loop is broadcast
// ds_read_b64, no global latency on the critical path.
__global__ __launch_bounds__(256) void k_rank2(const u64* __restrict__ cmp,
                                               const float* __restrict__ boxes,
                                               float* __restrict__ boxesS)
{
    __shared__ u64 sK[PRE_NMS];   // 48000 B
    int n = blockIdx.y;
    int t = threadIdx.x;
    const u64* K = cmp + (size_t)n * 8192;
    for (int j = t; j < PRE_NMS; j += 256) sK[j] = K[j];
    __syncthreads();
    int i = blockIdx.x * 256 + t;
    if (i >= PRE_NMS) return;
    u64 ki = sK[i];
    int rank = 0;
    #pragma unroll 8
    for (int j = 0; j < PRE_NMS; ++j)
        rank += (sK[j] < ki) ? 1 : 0;
    u32 idx = (u32)(ki & 0xFFFFFFFFu);
    ((float4*)boxesS)[(size_t)n * PRE_NMS + rank] =
        ((const float4*)boxes)[(size_t)n * HWA + idx];
}

// ---------------- IoU suppression bitmask: mask[n][i][w], upper triangle only ------
__global__ __launch_bounds__(64) void k_iou(const float* __restrict__ boxesS,
                                            u64* __restrict__ mask)
{
    __shared__ float4 cb[64];
    int w = blockIdx.x, ic = blockIdx.y, n = blockIdx.z;
    if (w < ic) return;                       // strictly-lower triangle: unused
    int t = threadIdx.x;
    const float4* B = (const float4*)boxesS + (size_t)n * PRE_NMS;
    int jc = w * 64 + t;
    cb[t] = (jc < PRE_NMS) ? B[jc] : make_float4(0.f, 0.f, 0.f, 0.f);
    __syncthreads();
    int i = ic * 64 + t;
    if (i >= PRE_NMS) return;
    float4 bb = B[i];
    float area1 = (bb.z - bb.x) * (bb.w - bb.y);
    u64 m = 0;
    #pragma unroll 8
    for (int j = 0; j < 64; ++j) {
        float4 o = cb[j];
        float ty_ = fmaxf(bb.x, o.x), tx_ = fmaxf(bb.y, o.y);
        float by_ = fminf(bb.z, o.z), bx_ = fminf(bb.w, o.w);
        float inter = fmaxf(by_ - ty_, 0.f) * fmaxf(bx_ - tx_, 0.f);
        float area2 = (o.z - o.x) * (o.w - o.y);
        float iou = inter / (area1 + area2 - inter + 1e-9f);
        if (iou > 0.7f) m |= (1ull << j);
    }
    mask[((size_t)n * PRE_NMS + i) * NWORD + w] = m;
}

// ---------------- batched greedy bitmask NMS: single wave, 8 candidates/round ------
__global__ __launch_bounds__(64) void k_nms4(const u64* __restrict__ mask,
                                             const int* __restrict__ nvalid,
                                             const float* __restrict__ boxesS,
                                             float* __restrict__ rois)
{
    int n = blockIdx.x, lane = threadIdx.x;
    int nv = nvalid[n];
    const u64* M = mask + (size_t)n * PRE_NMS * NWORD;
    const float4* B = (const float4*)boxesS + (size_t)n * PRE_NMS;

    auto vmask = [&](int w) -> u64 {
        int lo = w * 64;
        if (nv >= lo + 64) return ~0ull;
        if (nv <= lo) return 0ull;
        return (1ull << (nv - lo)) - 1ull;
    };
    u64 vm0 = vmask(lane);
    u64 vm1 = (lane < NWORD - 64) ? vmask(64 + lane) : 0ull;
    u64 rem0 = 0, rem1 = 0;

    int cnt = 0;
    while (cnt < POST_NMS) {
        // extract up to 8 lowest clear candidates
        u64 t0 = (~rem0) & vm0;
        u64 t1 = (~rem1) & vm1;
        int cand[8];
        int nc = 0;
        #pragma unroll
        for (int k = 0; k < 8; ++k) {
            u64 b0 = __ballot(t0 != 0);
            int c = -1;
            if (b0) {
                int l = __builtin_ctzll(b0);
                u64 w = __shfl(t0, l);
                c = l * 64 + __builtin_ctzll(w);
                if (lane == l) t0 &= t0 - 1;
            } else {
                u64 b1 = __ballot(t1 != 0);
                if (b1) {
                    int l = __builtin_ctzll(b1);
                    u64 w = __shfl(t1, l);
                    c = (64 + l) * 64 + __builtin_ctzll(w);
                    if (lane == l) t1 &= t1 - 1;
                }
            }
            if (c < 0) break;
            cand[nc++] = c;
        }
        if (nc == 0) break;

        // gather rows for all candidates (one latency window)
        u64 r0[8], r1[8];
        for (int k = 0; k < nc; ++k) {
            const u64* Mr = M + (size_t)cand[k] * NWORD;
            r0[k] = Mr[lane];
            r1[k] = (lane < NWORD - 64) ? Mr[64 + lane] : 0ull;
        }

        // chain greedily
        for (int k = 0; k < nc && cnt < POST_NMS; ++k) {
            int c = cand[k];
            int w = c >> 6, b = c & 63;
            u64 cw = (w < 64) ? __shfl(rem0, w) : __shfl(rem1, w - 64);
            if (!((cw >> b) & 1ull)) {
                if (lane == 0) {
                    float4 bb = B[c];
                    float* orow = rois + (size_t)(n * POST_NMS + cnt) * 4;
                    orow[0] = bb.x; orow[1] = bb.y; orow[2] = bb.z; orow[3] = bb.w;
                }
                rem0 |= r0[k];
                rem1 |= r1[k];
                cnt++;
            }
        }
    }
}

extern "C" void kernel_launch(void* const* d_in, const int* in_sizes, int n_in,
                              void* d_out, int out_size, void* d_ws, size_t ws_size,
                              hipStream_t stream)
{
    const float* x  = (const float*)d_in[0];
    const float* W1 = (const float*)d_in[1];
    const float* b1 = (const float*)d_in[2];
    const float* Ws = (const float*)d_in[3];
    const float* bs = (const float*)d_in[4];
    const float* Wl = (const float*)d_in[5];
    const float* bl = (const float*)d_in[6];
    const int* ih   = (const int*)d_in[7];
    const int* iw   = (const int*)d_in[8];
    float* out = (float*)d_out;
    char* ws = (char*)d_ws;

    // during conv:
    f16*   Wh2    = (f16*)  (ws);                 //  4,718,592 B (dead after conv)
    f16*   Wl2    = (f16*)  (ws + 4718592);       //  4,718,592 B (dead after conv)
    float* mid    = (float*)(ws + 9437184);       // 33,554,432 B (dead after hgemm)
    f16*   xh     = (f16*)  (ws + 42991616);      // 16,777,216 B (dead after conv)
    f16*   xl     = (f16*)  (ws + 59768832);      // 16,777,216 B (dead after conv)
    // after conv (reusing xh region at identical old offsets):
    float* boxes  = (float*)(ws + 42991616);      //  2,359,296 B
    u32*   key    = (u32*)  (ws + 45350912);      //    589,824 B
    u64*   cmp    = (u64*)  (ws + 45940736);      //    262,144 B
    float* boxesS = (float*)(ws + 46202880);      //    384,000 B
    int*   nval   = (int*)  (ws + 46586880);      //         16 B
    // reuse dead Wh2 region after conv:
    float* Wt2    = (float*)(ws);                 //    131,072 B [ci][co64]
    float* sraw   = (float*)(ws + 262144);        //  4,194,304 B [n][co64][px]
    // reuse dead mid region after hgemm:
    u64*   iomask = (u64*)  (ws + 9437184);       // 18,048,000 B

    k_prep_x<<<dim3(8, 64, 4), 256, 0, stream>>>(x, xh, xl);
    k_prep_w<<<1024, 256, 0, stream>>>(W1, Wh2, Wl2);
    k_conv_mfma<<<dim3(32, 8, 4), 256, 0, stream>>>(xh, xl, Wh2, Wl2, b1, mid);
    k_htrans<<<128, 256, 0, stream>>>(Ws, Wl, Wt2);
    k_hgemm<<<dim3(64, 4), 256, 0, stream>>>(mid, Wt2, sraw);
    k_decode<<<64, 256, 0, stream>>>(sraw, bs, bl, ih, iw, out, boxes, key);
    k_misc<<<144, 256, 0, stream>>>(out);
    k_select<<<4, 1024, 0, stream>>>(key, cmp, nval);
    k_rank2<<<dim3(24, NIMG), 256, 0, stream>>>(cmp, boxes, boxesS);
    k_iou<<<dim3(NWORD, NWORD, NIMG), 64, 0, stream>>>(boxesS, iomask);
    k_nms4<<<NIMG, 64, 0, stream>>>(iomask, nval, boxesS, out + OFF2);
}